// Round 9
// baseline (58.767 us; speedup 1.0000x reference)
//
#include <hip/hip_runtime.h>
#include <hip/hip_bf16.h>

#define ALPHA_ (-30.0f)
#define EPS_ (1e-4f)
#define LOG2E_ (1.4426950408889634f)

typedef short bf16x8 __attribute__((ext_vector_type(8)));
typedef float f32x4 __attribute__((ext_vector_type(4)));
typedef float f32x2 __attribute__((ext_vector_type(2)));

__device__ __forceinline__ short f2bf(float f) {
  __hip_bfloat16 h = __float2bfloat16(f);
  return __builtin_bit_cast(short, h);
}

__device__ __forceinline__ bf16x8 ld_a(const short* p) {
  int2 lo = *reinterpret_cast<const int2*>(p);      // 8B aligned
  int2 hi = *reinterpret_cast<const int2*>(p + 4);
  union { int i[4]; bf16x8 v; } u;
  u.i[0] = lo.x; u.i[1] = lo.y; u.i[2] = hi.x; u.i[3] = hi.y;
  return u.v;
}

__device__ __forceinline__ bf16x8 ld_b(const short* p) {
  union { int4 i; bf16x8 v; } u;
  u.i = *reinterpret_cast<const int4*>(p);          // 16B aligned
  return u.v;
}

// LDS layout (bytes), total 36112 -> 4 blocks/CU with headroom:
//   XC  @ 0     : 4 copies x 2192 bf16 (copy c: Cc[j] = bf16(x[j+c]))  = 17536
//   PS  @ 17536 : prefix sums of x^2, f32[2049]+pad                    =  8208
//   SH  @ 25744 : this half's 32 shapelets bf16 [32][L] * (-2*CE)     <= 6144
//   SX  @ 25744 : CE*sumx2 f32[2048]  (overlays SH after B-frag load)  =  8192
//   S2  @ 33936 : CE*s2 f32[32]                                        =   128
//   RED @ 34064 : f32[512]                                             =  2048
#define XC_OFF 0
#define PS_OFF 17536
#define R2_OFF 25744
#define S2_OFF 33936
#define RED_OFF 34064
#define SMEM_BYTES 36112
#define CL 2192

// Block = (row n, scale, shapelet-half sg0); grid 512 x 6 = 3072 blocks
// (12 slots/CU). Wave wv=wg covers 32 windows (2 wtiles) x 32 shapelets
// (2 ntiles) per iter; NIT = 16 with exactly one masked tail iter.
// bfr KT*2 (<=24) + acc 4xf32x4 (16) ~= 40 AGPR; total ~110 -> 4-wave tier.
template <int L, int SCALE>
__device__ __forceinline__ void feat_impl(const float* __restrict__ series,
                                          const float* __restrict__ shp,
                                          float* __restrict__ F, char* smem,
                                          int sg0) {
  constexpr int T = 2048;
  constexpr int W = T - L + 1;
  constexpr int KT = L / 32;
  constexpr int M = W / 128;           // = 15 full iters for all L
  constexpr float CE = ALPHA_ * LOG2E_ / (float)L;  // < 0
  constexpr float SCL = -2.0f * CE;

  short* xc = (short*)(smem + XC_OFF);
  float* ps = (float*)(smem + PS_OFF);
  short* sh = (short*)(smem + R2_OFF);
  float* sx = (float*)(smem + R2_OFF);
  float* s2 = (float*)(smem + S2_OFF);
  float* red = (float*)(smem + RED_OFF);

  const int n = blockIdx.x;
  const int tid = threadIdx.x;
  const int lane = tid & 63;
  const int wg = tid >> 6;             // window group (32 windows each)
  const int col = lane & 15;
  const int kg = lane >> 4;

  // ---------- phase A: load row, scan x^2, 4 shifted bf16 copies ----------
  const float* srow = series + (size_t)n * T;
  float4 v0 = *reinterpret_cast<const float4*>(srow + tid * 8);
  float4 v1 = *reinterpret_cast<const float4*>(srow + tid * 8 + 4);
  float xv[8] = {v0.x, v0.y, v0.z, v0.w, v1.x, v1.y, v1.z, v1.w};
  short bv8[12];
#pragma unroll
  for (int i = 0; i < 8; ++i) bv8[i] = f2bf(xv[i]);
  if (tid < 255) {  // next 4 elements for shifted copies (0 past row end)
    float4 ve = *reinterpret_cast<const float4*>(srow + tid * 8 + 8);
    bv8[8] = f2bf(ve.x); bv8[9] = f2bf(ve.y);
    bv8[10] = f2bf(ve.z); bv8[11] = f2bf(ve.w);
  } else {
    bv8[8] = bv8[9] = bv8[10] = bv8[11] = 0;
  }

  float loc[8];
  float run = 0.f;
#pragma unroll
  for (int i = 0; i < 8; ++i) {
    run = fmaf(xv[i], xv[i], run);
    loc[i] = run;
  }
  // wave-level inclusive scan of per-thread sums
  float sc = run;
#pragma unroll
  for (int off = 1; off < 64; off <<= 1) {
    float t = __shfl_up(sc, off, 64);
    if (lane >= off) sc += t;
  }
  if (lane == 63) red[wg] = sc;
  __syncthreads();
  float wb0 = 0.f;
  for (int w = 0; w < wg; ++w) wb0 += red[w];
  float excl = wb0 + sc - run;
#pragma unroll
  for (int i = 0; i < 8; ++i) ps[tid * 8 + 1 + i] = excl + loc[i];
  if (tid == 0) ps[0] = 0.f;

#pragma unroll
  for (int c = 0; c < 4; ++c) {  // one ds_write_b128 per copy
    union { short s[8]; int4 q; } u;
#pragma unroll
    for (int i = 0; i < 8; ++i) u.s[i] = bv8[i + c];
    *reinterpret_cast<int4*>(xc + c * CL + tid * 8) = u.q;
  }
  if (tid < CL - 2048) {
    int j = 2048 + tid;
#pragma unroll
    for (int c = 0; c < 4; ++c) xc[c * CL + j] = 0;
  }

  // stage this half's 32 shapelets (pre-scaled by -2*CE); s2 partials
  const float* shB = shp + sg0 * 32 * L;
  {
    constexpr int NE = 32 * L;  // multiple of 1024
    for (int i4 = tid * 4; i4 < NE; i4 += 1024) {
      float4 v = *reinterpret_cast<const float4*>(shB + i4);
      union { short s[4]; int2 q; } u;
      u.s[0] = f2bf(v.x * SCL); u.s[1] = f2bf(v.y * SCL);
      u.s[2] = f2bf(v.z * SCL); u.s[3] = f2bf(v.w * SCL);
      *reinterpret_cast<int2*>(sh + i4) = u.q;
    }
  }
  {
    constexpr int LQ = L / 8;  // 8 threads per shapelet
    const float* sp = shB + (tid & 31) * L + (tid >> 5) * LQ;
    float s = 0.f;
#pragma unroll
    for (int l = 0; l < LQ; ++l) s = fmaf(sp[l], sp[l], s);
    red[256 + tid] = s;  // red[0..3] holds scan partials this phase
  }
  __syncthreads();
  if (tid < 32) {
    float s = 0.f;
#pragma unroll
    for (int p = 0; p < 8; ++p) s += red[256 + p * 32 + tid];
    s2[tid] = CE * s;
  }
  __syncthreads();

  // ---------- B fragments + C-init to registers ----------
  bf16x8 bfr[KT][2];
#pragma unroll
  for (int kt = 0; kt < KT; ++kt)
#pragma unroll
    for (int j = 0; j < 2; ++j)
      bfr[kt][j] = ld_b(sh + (j * 16 + col) * L + kt * 32 + kg * 8);
  float s2c[2];
#pragma unroll
  for (int j = 0; j < 2; ++j) s2c[j] = s2[j * 16 + col];
  __syncthreads();

  // ---------- SX overlays SH ----------
  for (int w = tid; w < 2048; w += 256)
    sx[w] = (w < W) ? CE * (ps[w + L] - ps[w]) : 0.f;
  __syncthreads();

  // ---------- main loop (barrier-free): 2 wtiles x 2 ntiles ----------
  const int cc = lane & 3;
  const short* ap = xc + cc * CL + (col - cc) + 8 * kg + wg * 32;
  const float* sp2 = sx + wg * 32 + kg * 4;

  f32x2 esP[2], dsP[2];
#pragma unroll
  for (int j = 0; j < 2; ++j) {
    esP[j] = (f32x2){0.f, 0.f};
    dsP[j] = (f32x2){0.f, 0.f};
  }

  for (int it = 0; it < M; ++it) {  // fully-valid iterations: no masking
    f32x4 acc[2][2];
#pragma unroll
    for (int t = 0; t < 2; ++t)
#pragma unroll
      for (int j = 0; j < 2; ++j)
        acc[t][j] = (f32x4){s2c[j], s2c[j], s2c[j], s2c[j]};
#pragma unroll
    for (int kt = 0; kt < KT; ++kt) {
      bf16x8 a0 = ld_a(ap + kt * 32);
      bf16x8 a1 = ld_a(ap + 16 + kt * 32);
#pragma unroll
      for (int j = 0; j < 2; ++j) {
        acc[0][j] = __builtin_amdgcn_mfma_f32_16x16x32_bf16(a0, bfr[kt][j],
                                                            acc[0][j], 0, 0, 0);
        acc[1][j] = __builtin_amdgcn_mfma_f32_16x16x32_bf16(a1, bfr[kt][j],
                                                            acc[1][j], 0, 0, 0);
      }
    }
    float4 sv0 = *reinterpret_cast<const float4*>(sp2);
    float4 sv1 = *reinterpret_cast<const float4*>(sp2 + 16);
    f32x2 sxa[2][2] = {{{sv0.x, sv0.y}, {sv0.z, sv0.w}},
                       {{sv1.x, sv1.y}, {sv1.z, sv1.w}}};
#pragma unroll
    for (int t = 0; t < 2; ++t) {
#pragma unroll
      for (int j = 0; j < 2; ++j) {
        f32x2 u0 = (f32x2){acc[t][j][0], acc[t][j][1]} + sxa[t][0];
        f32x2 u1 = (f32x2){acc[t][j][2], acc[t][j][3]} + sxa[t][1];
        f32x2 e0, e1;
        e0.x = __builtin_amdgcn_exp2f(u0.x);
        e0.y = __builtin_amdgcn_exp2f(u0.y);
        e1.x = __builtin_amdgcn_exp2f(u1.x);
        e1.y = __builtin_amdgcn_exp2f(u1.y);
        e0 += (f32x2){EPS_, EPS_};
        e1 += (f32x2){EPS_, EPS_};
        esP[j] += e0;
        esP[j] += e1;
        dsP[j] = __builtin_elementwise_fma(u0, e0, dsP[j]);
        dsP[j] = __builtin_elementwise_fma(u1, e1, dsP[j]);
      }
    }
    ap += 128;
    sp2 += 128;
  }
  {  // single tail iter: per-element valid mask
    f32x4 acc[2][2];
#pragma unroll
    for (int t = 0; t < 2; ++t)
#pragma unroll
      for (int j = 0; j < 2; ++j)
        acc[t][j] = (f32x4){s2c[j], s2c[j], s2c[j], s2c[j]};
#pragma unroll
    for (int kt = 0; kt < KT; ++kt) {
      bf16x8 a0 = ld_a(ap + kt * 32);
      bf16x8 a1 = ld_a(ap + 16 + kt * 32);
#pragma unroll
      for (int j = 0; j < 2; ++j) {
        acc[0][j] = __builtin_amdgcn_mfma_f32_16x16x32_bf16(a0, bfr[kt][j],
                                                            acc[0][j], 0, 0, 0);
        acc[1][j] = __builtin_amdgcn_mfma_f32_16x16x32_bf16(a1, bfr[kt][j],
                                                            acc[1][j], 0, 0, 0);
      }
    }
#pragma unroll
    for (int t = 0; t < 2; ++t) {
      const int wb = M * 128 + wg * 32 + t * 16 + kg * 4;
      float4 sv = *reinterpret_cast<const float4*>(sp2 + t * 16);
      const float svr[4] = {sv.x, sv.y, sv.z, sv.w};
#pragma unroll
      for (int j = 0; j < 2; ++j) {
#pragma unroll
        for (int r = 0; r < 4; ++r) {
          float u = acc[t][j][r] + svr[r];
          float e = __builtin_amdgcn_exp2f(u) + EPS_;
          float em = ((wb + r) < W) ? e : 0.f;
          esP[j].x += em;
          dsP[j].x = fmaf(u, em, dsP[j].x);
        }
      }
    }
  }

  // ---------- reduce: shfl over kg, LDS over wg ----------
  constexpr float ALc = ALPHA_ * LOG2E_;
  float fe[2], fd[2];
#pragma unroll
  for (int j = 0; j < 2; ++j) {
    float es = esP[j].x + esP[j].y;
    float ds = dsP[j].x + dsP[j].y;
    es += __shfl_xor(es, 16, 64);
    es += __shfl_xor(es, 32, 64);
    ds += __shfl_xor(ds, 16, 64);
    ds += __shfl_xor(ds, 32, 64);
    fe[j] = es;
    fd[j] = ds;
  }
  __syncthreads();
  if (lane < 16) {
#pragma unroll
    for (int j = 0; j < 2; ++j) {
      int slot = (wg * 2 + j) * 16 + lane;
      red[slot] = fe[j];
      red[128 + slot] = fd[j];
    }
  }
  __syncthreads();
  if (tid < 32) {
    const int j = tid >> 4, c = tid & 15;
    float es = 0.f, ds = 0.f;
#pragma unroll
    for (int w = 0; w < 4; ++w) {
      int slot = (w * 2 + j) * 16 + c;
      es += red[slot];
      ds += red[128 + slot];
    }
    F[n * 192 + SCALE * 64 + sg0 * 32 + tid] = ds / (es * ALc);
  }
}

__global__ void __launch_bounds__(256, 2)
feat_kernel(const float* __restrict__ series, const float* __restrict__ shp1,
            const float* __restrict__ shp2, const float* __restrict__ shp3,
            float* __restrict__ F) {
  __shared__ __align__(16) char smem[SMEM_BYTES];
  const int sg0 = blockIdx.y & 1;
  const int scale = blockIdx.y >> 1;
  if (scale == 0)
    feat_impl<32, 0>(series, shp1, F, smem, sg0);
  else if (scale == 1)
    feat_impl<64, 1>(series, shp2, F, smem, sg0);
  else
    feat_impl<96, 2>(series, shp3, F, smem, sg0);
}

// ---------------------------------------------------------------------------
// Logits + softmax: out[n, :] = softmax(F[n, :] @ W + b)
// ---------------------------------------------------------------------------
__global__ void __launch_bounds__(64) logits_kernel(const float* __restrict__ F,
                                                    const float* __restrict__ Wm,
                                                    const float* __restrict__ bv,
                                                    float* __restrict__ out) {
  __shared__ float Ws[1920];
  __shared__ float bs[16];
  const int tid = threadIdx.x;
  for (int i = tid; i < 1920; i += 64) Ws[i] = Wm[i];
  if (tid < 10) bs[tid] = bv[tid];
  __syncthreads();

  const int n = blockIdx.x * 64 + tid;  // grid.x == 8 -> n in [0, 512)
  float acc[10];
#pragma unroll
  for (int c = 0; c < 10; ++c) acc[c] = bs[c];
  const float* f = F + n * 192;
  for (int j = 0; j < 192; j += 4) {
    float4 v = *reinterpret_cast<const float4*>(f + j);
#pragma unroll
    for (int c = 0; c < 10; ++c)
      acc[c] += v.x * Ws[(j + 0) * 10 + c] + v.y * Ws[(j + 1) * 10 + c] +
                v.z * Ws[(j + 2) * 10 + c] + v.w * Ws[(j + 3) * 10 + c];
  }
  float m = acc[0];
#pragma unroll
  for (int c = 1; c < 10; ++c) m = fmaxf(m, acc[c]);
  float s = 0.f;
  float e[10];
#pragma unroll
  for (int c = 0; c < 10; ++c) {
    e[c] = exp2f((acc[c] - m) * LOG2E_);
    s += e[c];
  }
  float inv = 1.f / s;
#pragma unroll
  for (int c = 0; c < 10; ++c) out[n * 10 + c] = e[c] * inv;
}

extern "C" void kernel_launch(void* const* d_in, const int* in_sizes, int n_in,
                              void* d_out, int out_size, void* d_ws, size_t ws_size,
                              hipStream_t stream) {
  const float* series = (const float*)d_in[0];  // [512, 2048]
  const float* shp1 = (const float*)d_in[1];    // [64, 32]
  const float* shp2 = (const float*)d_in[2];    // [64, 64]
  const float* shp3 = (const float*)d_in[3];    // [64, 96]
  const float* Wm = (const float*)d_in[4];      // [192, 10]
  const float* bv = (const float*)d_in[5];      // [10]
  float* out = (float*)d_out;                   // [512, 10] f32
  float* F = (float*)d_ws;                      // [512, 192] features

  feat_kernel<<<dim3(512, 6), 256, 0, stream>>>(series, shp1, shp2, shp3, F);
  logits_kernel<<<8, 64, 0, stream>>>(F, Wm, bv, out);
}